// Round 5
// baseline (256.670 us; speedup 1.0000x reference)
//
#include <hip/hip_runtime.h>
#include <cstdint>
#include <cstddef>

#define NP    1024
#define FD    10
#define NV    4
#define BSZ   128
#define NSET  1024          // 512 pairs x {goal, state}
#define TPB   256
#define RPT   2             // rows per thread (512 rows per block)

// d_ws layout (20 MB):
//   vis2 : [NSET][NP] float4  (-2 * normalized vis)   @ 0        (16 MB)
//   cs   : [NSET][NP] float   (||vis||^2)             @ 16777216 ( 4 MB)
#define OFF_CS 16777216

// ext-vector float4 + constant-address-space pointer: uniform loads from
// AS(4) ALWAYS select the scalar path (s_load_dwordx16 -> SGPRs), so the
// 64-lane broadcast of column data costs nothing on the vector pipes.
typedef float fv4 __attribute__((ext_vector_type(4)));
typedef const fv4 __attribute__((address_space(4)))* c4p;

// Set id s: pair = s>>1; (s&1)==1 -> state (achieved), ==0 -> goal (desired).
// pairs-block bid: pd = bid>>1 (cols = set[pd], rows = set[pd^1]), half = bid&1.

extern "C" __global__ __launch_bounds__(256)
void chamfer_stage(const float* __restrict__ ag, const float* __restrict__ dg,
                   const float* __restrict__ nmean, const float* __restrict__ nstd,
                   float* __restrict__ vis2o, float* __restrict__ cso)
{
    __shared__ float raw[NP * FD];          // 40 KB raw particle block
    const int s   = blockIdx.x;             // set id 0..1023
    const int tid = threadIdx.x;
    const float4* src = (const float4*)(((s & 1) ? ag : dg) + (size_t)(s >> 1) * (NP * FD));
    float4* lraw = (float4*)raw;
#pragma unroll
    for (int i = 0; i < 10; ++i)            // 2560 float4s, fully coalesced
        lraw[tid + 256 * i] = src[tid + 256 * i];

    float st0 = -2.0f * nstd[5], mn0 = -2.0f * nmean[5];
    float st1 = -2.0f * nstd[6], mn1 = -2.0f * nmean[6];
    float st2 = -2.0f * nstd[7], mn2 = -2.0f * nmean[7];
    float st3 = -2.0f * nstd[8], mn3 = -2.0f * nmean[8];
    __syncthreads();

    fv4*   vout = (fv4*)vis2o + (size_t)s * NP;
    float* cout = cso + (size_t)s * NP;
    for (int n = tid; n < NP; n += 256) {   // LDS stride 10 -> 2-way conflict (free)
        float v0 = fmaf(raw[FD * n + 5], st0, mn0);
        float v1 = fmaf(raw[FD * n + 6], st1, mn1);
        float v2 = fmaf(raw[FD * n + 7], st2, mn2);
        float v3 = fmaf(raw[FD * n + 8], st3, mn3);
        fv4 v; v.x = v0; v.y = v1; v.z = v2; v.w = v3;
        vout[n] = v;
        // vis2 = -2*vis -> ||vis||^2 = 0.25 * dot (same order as rounds 3/4)
        cout[n] = 0.25f * (v0 * v0 + v1 * v1 + v2 * v2 + v3 * v3);
    }
}

extern "C" __global__ __launch_bounds__(TPB, 8)
void chamfer_pairs(const float* __restrict__ vis2, const float* __restrict__ cs,
                   const float* __restrict__ ag, const float* __restrict__ dg,
                   const float* __restrict__ nmean, const float* __restrict__ nstd,
                   float* __restrict__ out /* [BSZ] pre-zeroed */)
{
    __shared__ float redbuf[TPB / 64];

    const int bid  = blockIdx.x;        // 0..2047
    const int pd   = bid >> 1;          // pair*2 + d
    const int half = bid & 1;           // which 512-row half
    const int pair = pd >> 1;
    const int d    = pd & 1;
    const int tid  = threadIdx.x;

    // Column set via constant-AS (scalar) loads; vector view kept for the
    // divergent epilogue replay (bit-identical data either way).
    c4p cvisS = (c4p)(uintptr_t)(vis2 + (size_t)pd * NP * 4);
    c4p ccsS  = (c4p)(uintptr_t)(cs   + (size_t)pd * NP);
    const float4* cvisV = (const float4*)(vis2 + (size_t)pd * NP * 4);
    const float*  ccsV  = cs + (size_t)pd * NP;
    const float4* rvis4 = (const float4*)(vis2 + (size_t)(pd ^ 1) * NP * 4);
    const float*  rcs   = cs + (size_t)(pd ^ 1) * NP;

    // Epilogue xy sources: d=0 rows=state(ag)/cols=goal(dg); d=1 swapped.
    const float* rxyg = ((d == 0) ? ag : dg) + (size_t)pair * (NP * FD);
    const float* cxyg = ((d == 0) ? dg : ag) + (size_t)pair * (NP * FD);

    float4 rv[RPT];
    float  rthr[RPT];    // (rs + bestd') > 6  <=>  bestd' > 6 - rs
    float  bestd[RPT];
    int    bblk[RPT];
#pragma unroll
    for (int r = 0; r < RPT; ++r) {
        int n = half * 512 + tid + TPB * r;
        float4 t = rvis4[n];                     // stored as -2*vis; unscale for rows
        rv[r] = make_float4(-0.5f * t.x, -0.5f * t.y, -0.5f * t.z, -0.5f * t.w);
        rthr[r] = 6.0f - rcs[n];
        bestd[r] = 3.0e38f;
        bblk[r]  = 0;
    }

    for (int mb8 = 0; mb8 < NP / 8; ++mb8) {
        const int m = mb8 * 8;
        // Uniform constant-AS loads -> s_load_dwordx16 into SGPRs.
        fv4 c0 = cvisS[m + 0];
        fv4 c1 = cvisS[m + 1];
        fv4 c2 = cvisS[m + 2];
        fv4 c3 = cvisS[m + 3];
        fv4 c4 = cvisS[m + 4];
        fv4 c5 = cvisS[m + 5];
        fv4 c6 = cvisS[m + 6];
        fv4 c7 = cvisS[m + 7];
        fv4 csA = ccsS[mb8 * 2 + 0];
        fv4 csB = ccsS[mb8 * 2 + 1];
#pragma unroll
        for (int r = 0; r < RPT; ++r) {
            float4 v = rv[r];
            float d0 = fmaf(v.x, c0.x, csA.x); d0 = fmaf(v.y, c0.y, d0); d0 = fmaf(v.z, c0.z, d0); d0 = fmaf(v.w, c0.w, d0);
            float d1 = fmaf(v.x, c1.x, csA.y); d1 = fmaf(v.y, c1.y, d1); d1 = fmaf(v.z, c1.z, d1); d1 = fmaf(v.w, c1.w, d1);
            float d2 = fmaf(v.x, c2.x, csA.z); d2 = fmaf(v.y, c2.y, d2); d2 = fmaf(v.z, c2.z, d2); d2 = fmaf(v.w, c2.w, d2);
            float d3 = fmaf(v.x, c3.x, csA.w); d3 = fmaf(v.y, c3.y, d3); d3 = fmaf(v.z, c3.z, d3); d3 = fmaf(v.w, c3.w, d3);
            float d4 = fmaf(v.x, c4.x, csB.x); d4 = fmaf(v.y, c4.y, d4); d4 = fmaf(v.z, c4.z, d4); d4 = fmaf(v.w, c4.w, d4);
            float d5 = fmaf(v.x, c5.x, csB.y); d5 = fmaf(v.y, c5.y, d5); d5 = fmaf(v.z, c5.z, d5); d5 = fmaf(v.w, c5.w, d5);
            float d6 = fmaf(v.x, c6.x, csB.z); d6 = fmaf(v.y, c6.y, d6); d6 = fmaf(v.z, c6.z, d6); d6 = fmaf(v.w, c6.w, d6);
            float d7 = fmaf(v.x, c7.x, csB.w); d7 = fmaf(v.y, c7.y, d7); d7 = fmaf(v.z, c7.z, d7); d7 = fmaf(v.w, c7.w, d7);
            // block-min via v_min3 tree (exact; no NaNs)
            float p0 = fminf(fminf(d0, d1), d2);
            float p1 = fminf(fminf(d3, d4), d5);
            float p2 = fminf(d6, d7);
            float bm = fminf(fminf(p0, p1), p2);
            bool lt = bm < bestd[r];             // strict < keeps FIRST block on ties
            bestd[r] = fminf(bestd[r], bm);
            bblk[r]  = lt ? m : bblk[r];
        }
    }

    // Epilogue: replay the winning block (identical fmaf chain on the same
    // staged bits -> bit-exact) to recover the first-tie index, then gather xy.
    const float std0 = nstd[0], mean0 = nmean[0];
    const float std1 = nstd[1], mean1 = nmean[1];
    float sum = 0.0f;
#pragma unroll
    for (int r = 0; r < RPT; ++r) {
        int n  = half * 512 + tid + TPB * r;
        int mb = bblk[r];
        float4 v = rv[r];
        float cse[8];
#pragma unroll
        for (int j = 0; j < 8; ++j) cse[j] = ccsV[mb + j];
        float dd[8];
#pragma unroll
        for (int j = 0; j < 8; ++j) {
            float4 c = cvisV[mb + j];            // divergent -> vector gather (L2-hot)
            float t = fmaf(v.x, c.x, cse[j]);
            t = fmaf(v.y, c.y, t);
            t = fmaf(v.z, c.z, t);
            t = fmaf(v.w, c.w, t);
            dd[j] = t;
        }
        int sel = 0;
#pragma unroll
        for (int j = 7; j >= 0; --j)             // descending: smallest j wins ties
            if (dd[j] == bestd[r]) sel = j;
        int idx = mb + sel;

        float gx = fmaf(cxyg[(size_t)idx * FD + 0], std0, mean0);
        float gy = fmaf(cxyg[(size_t)idx * FD + 1], std1, mean1);
        float ax = fmaf(rxyg[(size_t)n * FD + 0], std0, mean0);
        float ay = fmaf(rxyg[(size_t)n * FD + 1], std1, mean1);
        float dx = ax - gx;
        float dy = ay - gy;
        float dist = sqrtf(dx * dx + dy * dy);
        if (bestd[r] > rthr[r]) dist = 1.0f;     // min_d > LATENT_DIST_THRESHOLD
        sum += dist;
    }

    // Wave shuffle reduce, cross-wave via LDS, one atomic per block.
    for (int o = 32; o > 0; o >>= 1) sum += __shfl_down(sum, o, 64);
    if ((tid & 63) == 0) redbuf[tid >> 6] = sum;
    __syncthreads();
    if (tid == 0) {
        float s = redbuf[0] + redbuf[1] + redbuf[2] + redbuf[3];
        // out[b] = -(sum over 4 views x 2 dirs x 2 halves x 1024 rows) / 8192
        atomicAdd(&out[pair >> 2], s * (-1.0f / 8192.0f));
    }
}

extern "C" void kernel_launch(void* const* d_in, const int* in_sizes, int n_in,
                              void* d_out, int out_size, void* d_ws, size_t ws_size,
                              hipStream_t stream)
{
    const float* ag = (const float*)d_in[0];   // achieved_goal (128,4,1024,10)
    const float* dg = (const float*)d_in[1];   // desired_goal  (128,4,1024,10)
    const float* nm = (const float*)d_in[2];   // norm_mean (10,)
    const float* ns = (const float*)d_in[3];   // norm_std  (10,)

    char*  ws    = (char*)d_ws;
    float* vis2  = (float*)(ws);               // 16 MB
    float* csbuf = (float*)(ws + OFF_CS);      //  4 MB

    hipMemsetAsync(d_out, 0, BSZ * sizeof(float), stream);   // out is accumulated
    chamfer_stage<<<NSET, 256, 0, stream>>>(ag, dg, nm, ns, vis2, csbuf);
    chamfer_pairs<<<NSET * 2, TPB, 0, stream>>>(vis2, csbuf, ag, dg, nm, ns, (float*)d_out);
}

// Round 6
// 228.246 us; speedup vs baseline: 1.1245x; 1.1245x over previous
//
#include <hip/hip_runtime.h>
#include <cstdint>
#include <cstddef>

#define NP  1024
#define FD  10
#define NV  4
#define BSZ 128
#define TPB 128
#define RPT 8     // rows per thread: 128 threads x 8 = 1024 rows per (pair,dir)

typedef float v2f __attribute__((ext_vector_type(2)));
typedef float v4f __attribute__((ext_vector_type(4)));

// One block per (pair, dir): bid = pair*2 + d.
//   d=0: rows = state(ag), cols = goal(dg)   (reward_s2g)
//   d=1: rows = goal(dg),  cols = state(ag)  (reward_g2s)
// Shift-reduced distance: argmin_m [rs + cs_m - 2 r.c_m] == argmin_m [cs_m + r.c2_m]
// with c2 = -2*c staged in LDS as flat component arrays (which IS the packed-pair
// layout for v_pk_fma_f32). Tracker keeps the winning 8-col BLOCK; exact
// first-tie index is recovered by replaying the identical fmaf chain (bit-exact).
extern "C" __global__ __launch_bounds__(TPB, 2)
void chamfer_pairs(const float* __restrict__ ag, const float* __restrict__ dg,
                   const float* __restrict__ nmean, const float* __restrict__ nstd,
                   float* __restrict__ out /* [BSZ], pre-zeroed */)
{
    __shared__ float cxF[NP], cyF[NP], czF[NP], cwF[NP], csF[NP];  // 20 KB
    __shared__ float red[TPB / 64];

    const int bid  = blockIdx.x;        // 0..1023
    const int pair = bid >> 1;
    const int d    = bid & 1;
    const int tid  = threadIdx.x;

    const float* rowsrc = ((d == 0) ? ag : dg) + (size_t)pair * (NP * FD);
    const float* colsrc = ((d == 0) ? dg : ag) + (size_t)pair * (NP * FD);

    // Normalization constants (uniform -> scalar loads).
    const float s5 = -2.0f * nstd[5], m5 = -2.0f * nmean[5];
    const float s6 = -2.0f * nstd[6], m6 = -2.0f * nmean[6];
    const float s7 = -2.0f * nstd[7], m7 = -2.0f * nmean[7];
    const float s8 = -2.0f * nstd[8], m8 = -2.0f * nmean[8];
    const float std0 = nstd[0], mean0 = nmean[0];
    const float std1 = nstd[1], mean1 = nmean[1];

    // ---- Stage columns into LDS: t = fmaf(raw, -2std, -2mean); cs = 0.25*dot(t,t)
    for (int m = tid; m < NP; m += TPB) {
        const float* p = colsrc + (size_t)m * FD;
        float t0 = fmaf(p[5], s5, m5);
        float t1 = fmaf(p[6], s6, m6);
        float t2 = fmaf(p[7], s7, m7);
        float t3 = fmaf(p[8], s8, m8);
        cxF[m] = t0; cyF[m] = t1; czF[m] = t2; cwF[m] = t3;
        csF[m] = 0.25f * (t0 * t0 + t1 * t1 + t2 * t2 + t3 * t3);
    }

    // ---- Per-lane rows (same bit-exact chain: rv = -0.5*t, rss = 0.25*dot)
    float4 rv[RPT];
    float  rthr[RPT];
    float  bestd[RPT];
    int    bblk[RPT];
#pragma unroll
    for (int r = 0; r < RPT; ++r) {
        int n = tid + TPB * r;
        const float* p = rowsrc + (size_t)n * FD;
        float t0 = fmaf(p[5], s5, m5);
        float t1 = fmaf(p[6], s6, m6);
        float t2 = fmaf(p[7], s7, m7);
        float t3 = fmaf(p[8], s8, m8);
        rv[r] = make_float4(-0.5f * t0, -0.5f * t1, -0.5f * t2, -0.5f * t3);
        float rss = 0.25f * (t0 * t0 + t1 * t1 + t2 * t2 + t3 * t3);
        rthr[r] = 6.0f - rss;            // (rs + bestd') > 6  <=>  bestd' > 6 - rs
        bestd[r] = 3.0e38f;
        bblk[r]  = 0;
    }
    __syncthreads();

    const v4f* X4 = (const v4f*)cxF;
    const v4f* Y4 = (const v4f*)cyF;
    const v4f* Z4 = (const v4f*)czF;
    const v4f* W4 = (const v4f*)cwF;
    const v4f* S4 = (const v4f*)csF;

    // ---- Main loop: 8 columns per iter, wave-uniform b128 LDS broadcasts.
#pragma unroll 2
    for (int g = 0; g < NP / 8; ++g) {
        const int m = g * 8;
        v4f xA = X4[2 * g], xB = X4[2 * g + 1];
        v4f yA = Y4[2 * g], yB = Y4[2 * g + 1];
        v4f zA = Z4[2 * g], zB = Z4[2 * g + 1];
        v4f wA = W4[2 * g], wB = W4[2 * g + 1];
        v4f cA = S4[2 * g], cB = S4[2 * g + 1];
#pragma unroll
        for (int r = 0; r < RPT; ++r) {
            v2f vx = {rv[r].x, rv[r].x};
            v2f vy = {rv[r].y, rv[r].y};
            v2f vz = {rv[r].z, rv[r].z};
            v2f vw = {rv[r].w, rv[r].w};
            // per-element chain identical to rounds 3-5: fma(x)->fma(y)->fma(z)->fma(w) from cs
            v2f q0 = __builtin_elementwise_fma(vx, xA.lo, cA.lo);
            q0 = __builtin_elementwise_fma(vy, yA.lo, q0);
            q0 = __builtin_elementwise_fma(vz, zA.lo, q0);
            q0 = __builtin_elementwise_fma(vw, wA.lo, q0);
            v2f q1 = __builtin_elementwise_fma(vx, xA.hi, cA.hi);
            q1 = __builtin_elementwise_fma(vy, yA.hi, q1);
            q1 = __builtin_elementwise_fma(vz, zA.hi, q1);
            q1 = __builtin_elementwise_fma(vw, wA.hi, q1);
            v2f q2 = __builtin_elementwise_fma(vx, xB.lo, cB.lo);
            q2 = __builtin_elementwise_fma(vy, yB.lo, q2);
            q2 = __builtin_elementwise_fma(vz, zB.lo, q2);
            q2 = __builtin_elementwise_fma(vw, wB.lo, q2);
            v2f q3 = __builtin_elementwise_fma(vx, xB.hi, cB.hi);
            q3 = __builtin_elementwise_fma(vy, yB.hi, q3);
            q3 = __builtin_elementwise_fma(vz, zB.hi, q3);
            q3 = __builtin_elementwise_fma(vw, wB.hi, q3);
            // exact min tree (order-invariant value; no NaNs)
            v2f m01 = __builtin_elementwise_min(q0, q1);
            v2f m23 = __builtin_elementwise_min(q2, q3);
            v2f mm  = __builtin_elementwise_min(m01, m23);
            float bm = fminf(mm.x, mm.y);
            bool lt = bm < bestd[r];      // strict < keeps FIRST block on ties
            bestd[r] = fminf(bestd[r], bm);
            bblk[r]  = lt ? m : bblk[r];
        }
    }

    // ---- Epilogue: replay winning block (bit-exact chain) for the first-tie
    // index, gather xy from raw inputs, accumulate L2 distance.
    float sum = 0.0f;
#pragma unroll
    for (int r = 0; r < RPT; ++r) {
        int n  = tid + TPB * r;
        int mb = bblk[r];
        float4 v = rv[r];
        float dd[8];
#pragma unroll
        for (int j = 0; j < 8; ++j) {
            float t = fmaf(v.x, cxF[mb + j], csF[mb + j]);
            t = fmaf(v.y, cyF[mb + j], t);
            t = fmaf(v.z, czF[mb + j], t);
            t = fmaf(v.w, cwF[mb + j], t);
            dd[j] = t;
        }
        int sel = 0;
#pragma unroll
        for (int j = 7; j >= 0; --j)      // descending: smallest j wins ties
            if (dd[j] == bestd[r]) sel = j;
        int idx = mb + sel;

        float gx = fmaf(colsrc[(size_t)idx * FD + 0], std0, mean0);
        float gy = fmaf(colsrc[(size_t)idx * FD + 1], std1, mean1);
        float ax = fmaf(rowsrc[(size_t)n * FD + 0], std0, mean0);
        float ay = fmaf(rowsrc[(size_t)n * FD + 1], std1, mean1);
        float dx = ax - gx;
        float dy = ay - gy;
        float dist = sqrtf(dx * dx + dy * dy);
        if (bestd[r] > rthr[r]) dist = 1.0f;   // min_d > LATENT_DIST_THRESHOLD
        sum += dist;
    }

    // ---- Reduce: wave shuffle, cross-wave LDS, one atomic per block.
    for (int o = 32; o > 0; o >>= 1) sum += __shfl_down(sum, o, 64);
    if ((tid & 63) == 0) red[tid >> 6] = sum;
    __syncthreads();
    if (tid == 0) {
        float s = red[0] + red[1];
        // out[b] = -(sum over 4 views x 2 dirs x 1024 rows) / 8192
        atomicAdd(&out[pair >> 2], s * (-1.0f / 8192.0f));
    }
}

extern "C" void kernel_launch(void* const* d_in, const int* in_sizes, int n_in,
                              void* d_out, int out_size, void* d_ws, size_t ws_size,
                              hipStream_t stream)
{
    const float* ag = (const float*)d_in[0];   // achieved_goal (128,4,1024,10)
    const float* dg = (const float*)d_in[1];   // desired_goal  (128,4,1024,10)
    const float* nm = (const float*)d_in[2];   // norm_mean (10,)
    const float* ns = (const float*)d_in[3];   // norm_std  (10,)

    hipMemsetAsync(d_out, 0, BSZ * sizeof(float), stream);   // out is accumulated
    chamfer_pairs<<<BSZ * NV * 2, TPB, 0, stream>>>(ag, dg, nm, ns, (float*)d_out);
}